// Round 3
// baseline (529.440 us; speedup 1.0000x reference)
//
#include <hip/hip_runtime.h>

// BacklashNet: per-row nonlinear scan, parallelized by chained speculative
// chunking (Jacobi sweeps) + bitwise-validated sequential stitch + fix pass.
//
// Step (bit-exact vs JAX/numpy fp32 reference, no FMA contraction):
//   lo=fl(fl(m_lo*x)+fl(m_lo*c_lo)); up analog; f1=(lo<=prev); f2=(fl(prev-A2)<=muc)
//   out = f1 ? (f2 ? fl(fl(lo+A2)+muc) : lo) : (f2 ? up : prev)
// Effective map: out = clamp(prev, up(x), lo(x)) (plus a 3-constant branch when
// lo<=up), so two trajectories merge (bitwise) once a shared clip catches both.
// Measured per-64-step merge failure ~10% (R2 FETCH evidence); chaining k sweeps
// gives ~0.1^k residual. Validation is bitwise equality of speculated entries;
// mismatches fall back to inline recompute (pass_b) and per-chunk output rewrite
// (pass_cfix) — sound regardless of merge statistics.
//
// Workspace layout (4 MB): e0 | e1 | e2 | e3, each B*NC floats = 1 MB.
//   After the sweeps, e0 is reused as `ent` (true chunk entries) and e1 as
//   `flag` (int 0/1 speculation-ok), both written by pass_b before cfix reads.

namespace {

constexpr int kB   = 2048;
constexpr int kT   = 8192;
constexpr int kL   = 64;         // chunk length (timesteps)
constexpr int kNC  = kT / kL;    // 128 chunks per row
constexpr int kRC  = kB * kNC;   // 262144 row-chunks
// thread mapping in chunk-parallel kernels: tid = c*kB + r  (r fast)
// => e-array accesses [c][r] are fully coalesced.

__device__ __forceinline__ float bstep(float xv, float prev, float m_lo, float m_up,
                                       float mlc, float muc) {
  float A1 = __fmul_rn(m_lo, xv);
  float B1 = __fadd_rn(A1, mlc);                  // "lo"
  float A2 = __fmul_rn(m_up, xv);
  float B2 = __fadd_rn(A2, muc);                  // "up"
  float C  = __fadd_rn(__fadd_rn(B1, A2), muc);   // f1&f2 case, exact ref ordering
  float u  = __fsub_rn(prev, A2);
  bool  f1 = (B1 <= prev);                        // sign-exact: s1 <= 0
  bool  f2 = (u <= muc);                          // sign-exact: s2 <= 0
  float hi = f2 ? C  : B1;
  float lo = f2 ? B2 : prev;
  return f1 ? hi : lo;
}

template <bool WRITE>
__device__ __forceinline__ float run_chunk(const float4* __restrict__ xv,
                                           float4* __restrict__ ov, float p,
                                           float m_lo, float m_up, float mlc, float muc) {
#pragma unroll
  for (int i = 0; i < kL / 4; ++i) {
    float4 a = xv[i];
    float4 o;
    p = bstep(a.x, p, m_lo, m_up, mlc, muc); o.x = p;
    p = bstep(a.y, p, m_lo, m_up, mlc, muc); o.y = p;
    p = bstep(a.z, p, m_lo, m_up, mlc, muc); o.z = p;
    p = bstep(a.w, p, m_lo, m_up, mlc, muc); o.w = p;
    if (WRITE) ov[i] = o;
  }
  return p;
}

// Sweep 0: every chunk from guess (true p0 for c==0, else 0.0).
__global__ __launch_bounds__(256) void sweep0(
    const float* __restrict__ x, const float* __restrict__ p0,
    const float* __restrict__ w, float* __restrict__ e0) {
  const int tid = blockIdx.x * 256 + threadIdx.x;
  const int r = tid & (kB - 1), c = tid >> 11;
  const float m_lo = w[0], m_up = w[1];
  const float mlc = __fmul_rn(m_lo, w[2]), muc = __fmul_rn(m_up, w[3]);
  const float entry = (c == 0) ? p0[r] : 0.0f;
  const float4* xv = reinterpret_cast<const float4*>(x + (size_t)r * kT + c * kL);
  e0[tid] = run_chunk<false>(xv, nullptr, entry, m_lo, m_up, mlc, muc);
}

// Sweeps 1..2: every chunk from the previous sweep's exit of chunk c-1.
__global__ __launch_bounds__(256) void sweepN(
    const float* __restrict__ x, const float* __restrict__ p0,
    const float* __restrict__ w, const float* __restrict__ ein,
    float* __restrict__ eout) {
  const int tid = blockIdx.x * 256 + threadIdx.x;
  const int r = tid & (kB - 1), c = tid >> 11;
  const float m_lo = w[0], m_up = w[1];
  const float mlc = __fmul_rn(m_lo, w[2]), muc = __fmul_rn(m_up, w[3]);
  const float entry = (c == 0) ? p0[r] : ein[tid - kB];
  const float4* xv = reinterpret_cast<const float4*>(x + (size_t)r * kT + c * kL);
  eout[tid] = run_chunk<false>(xv, nullptr, entry, m_lo, m_up, mlc, muc);
}

// Sweep 3: from e2[c-1]; also speculatively writes the output interior.
__global__ __launch_bounds__(256) void sweep3w(
    const float* __restrict__ x, const float* __restrict__ p0,
    const float* __restrict__ w, const float* __restrict__ e2,
    float* __restrict__ e3, float* __restrict__ out) {
  const int tid = blockIdx.x * 256 + threadIdx.x;
  const int r = tid & (kB - 1), c = tid >> 11;
  const float m_lo = w[0], m_up = w[1];
  const float mlc = __fmul_rn(m_lo, w[2]), muc = __fmul_rn(m_up, w[3]);
  const float entry = (c == 0) ? p0[r] : e2[tid - kB];
  const float4* xv = reinterpret_cast<const float4*>(x + (size_t)r * kT + c * kL);
  float4* ov = reinterpret_cast<float4*>(out + (size_t)r * kT + c * kL);
  e3[tid] = run_chunk<true>(xv, ov, entry, m_lo, m_up, mlc, muc);
}

// pass_b: per-row serial stitch. Accept chunk c in O(1) iff the entry S3 used
// (e2[c-1]) bitwise-equals the true running state; else inline recompute (rare).
// Records true entries and ok-flags for the fix pass.
__global__ __launch_bounds__(64) void pass_b(
    const float* __restrict__ x, const float* __restrict__ p0,
    const float* __restrict__ w, const float* __restrict__ e2,
    const float* __restrict__ e3, float* __restrict__ ent,
    int* __restrict__ flag) {
  const int r = blockIdx.x * 64 + threadIdx.x;
  const float m_lo = w[0], m_up = w[1];
  const float mlc = __fmul_rn(m_lo, w[2]), muc = __fmul_rn(m_up, w[3]);
  float t = p0[r];
#pragma unroll 1
  for (int c = 0; c < kNC; ++c) {
    const int idx = c * kB + r;                      // coalesced across lanes
    const float used = (c == 0) ? p0[r] : e2[idx - kB];
    const float ex   = e3[idx];
    ent[idx] = t;
    const bool ok = (used == t);
    flag[idx] = ok ? 1 : 0;
    if (ok) {
      t = ex;  // S3 ran this chunk from exactly t => its outputs + exit are true
    } else {
      const float4* xv = reinterpret_cast<const float4*>(x + (size_t)r * kT + c * kL);
      t = run_chunk<false>(xv, nullptr, t, m_lo, m_up, mlc, muc);
    }
  }
}

// pass_cfix: rewrite only the chunks whose speculative entry was wrong.
__global__ __launch_bounds__(256) void pass_cfix(
    const float* __restrict__ x, const float* __restrict__ w,
    const float* __restrict__ ent, const int* __restrict__ flag,
    float* __restrict__ out) {
  const int tid = blockIdx.x * 256 + threadIdx.x;
  if (flag[tid] != 0) return;
  const int r = tid & (kB - 1), c = tid >> 11;
  const float m_lo = w[0], m_up = w[1];
  const float mlc = __fmul_rn(m_lo, w[2]), muc = __fmul_rn(m_up, w[3]);
  const float4* xv = reinterpret_cast<const float4*>(x + (size_t)r * kT + c * kL);
  float4* ov = reinterpret_cast<float4*>(out + (size_t)r * kT + c * kL);
  run_chunk<true>(xv, ov, ent[tid], m_lo, m_up, mlc, muc);
}

}  // namespace

extern "C" void kernel_launch(void* const* d_in, const int* in_sizes, int n_in,
                              void* d_out, int out_size, void* d_ws, size_t ws_size,
                              hipStream_t stream) {
  const float* x  = (const float*)d_in[0];   // (B, T, 1) fp32
  const float* p0 = (const float*)d_in[1];   // (B, 1, 1) fp32
  const float* w  = (const float*)d_in[2];   // (4,) fp32
  float* out = (float*)d_out;                // (B, T, 1) fp32
  (void)in_sizes; (void)n_in; (void)out_size; (void)ws_size;

  float* e0 = (float*)d_ws;        // 1 MB   (reused as `ent` after sweeps)
  float* e1 = e0 + kRC;            // 1 MB   (reused as `flag` after sweeps)
  float* e2 = e1 + kRC;            // 1 MB
  float* e3 = e2 + kRC;            // 1 MB
  float* ent  = e0;
  int*   flag = (int*)e1;

  const int nb = kRC / 256;        // 1024 blocks
  sweep0 <<<nb, 256, 0, stream>>>(x, p0, w, e0);
  sweepN <<<nb, 256, 0, stream>>>(x, p0, w, e0, e1);
  sweepN <<<nb, 256, 0, stream>>>(x, p0, w, e1, e2);
  sweep3w<<<nb, 256, 0, stream>>>(x, p0, w, e2, e3, out);
  pass_b <<<kB / 64, 64, 0, stream>>>(x, p0, w, e2, e3, ent, flag);
  pass_cfix<<<nb, 256, 0, stream>>>(x, w, ent, flag, out);
}

// Round 4
// 261.588 us; speedup vs baseline: 2.0239x; 2.0239x over previous
//
#include <hip/hip_runtime.h>

// BacklashNet: per-row nonlinear scan = out_t = clamp-ish(prev; up_t, lo_t).
// Parallelization: speculative chunking + EXACT O(1) identity-interval
// acceptance for "parked" states (the R2/R3-measured persistent ~10-13%
// mismatch mode), + bitwise-validated speculation for merging chunks, +
// rare serial fallback. Bit-exact step (no FMA contraction, ref ordering):
//   A1=fl(m_lo*x); B1=fl(A1+mlc)  ["lo"]
//   A2=fl(m_up*x); B2=fl(A2+muc)  ["up"]; C=fl(fl(B1+A2)+muc)
//   f1=(B1<=p)  [sign-exact s1<=0];  f2=(fl(p-A2)<=muc)  [sign-exact s2<=0]
//   out = f1 ? (f2?C:B1) : (f2?B2:p)
// Identity step for entry p  <=>  p < B1_t  AND  fl(p-A2_t) > muc.
// Whole-chunk identity <=> p < min_t B1_t AND fl(p - max_t A2_t) > muc
// (RN sub is monotone in A2, binding step realizes equality => EXACT).
// Identity chunk => trajectory constant: outputs = entry, exit = entry.
//
// Workspace (5 MB): e0 | e1 | e2 | a2m | b1m, each B*NC floats.
// e0 is reused as `ent` (true chunk entries) after sweep1 consumed it.

namespace {

constexpr int kB  = 2048;
constexpr int kT  = 8192;
constexpr int kL  = 64;        // chunk length
constexpr int kNC = kT / kL;   // 128 chunks/row
constexpr int kRC = kB * kNC;  // 262144 row-chunks
// e/a2m/b1m storage layout: idx = c*kB + r  (r fast => pass_b coalesced).
// Chunk-parallel kernels map tid -> (r = tid>>7, c = tid&127) so a wave's
// 64 lanes stream a contiguous 16 KB x window (r fixed, c consecutive).

__device__ __forceinline__ float bstep(float xv, float prev, float m_lo, float m_up,
                                       float mlc, float muc) {
  float A1 = __fmul_rn(m_lo, xv);
  float B1 = __fadd_rn(A1, mlc);
  float A2 = __fmul_rn(m_up, xv);
  float B2 = __fadd_rn(A2, muc);
  float C  = __fadd_rn(__fadd_rn(B1, A2), muc);
  float u  = __fsub_rn(prev, A2);
  bool  f1 = (B1 <= prev);
  bool  f2 = (u <= muc);
  float hi = f2 ? C  : B1;
  float lo = f2 ? B2 : prev;
  return f1 ? hi : lo;
}

__device__ __forceinline__ float bstep_track(float xv, float prev, float m_lo, float m_up,
                                             float mlc, float muc,
                                             float& maxA2, float& minB1) {
  float A1 = __fmul_rn(m_lo, xv);
  float B1 = __fadd_rn(A1, mlc);
  float A2 = __fmul_rn(m_up, xv);
  float B2 = __fadd_rn(A2, muc);
  float C  = __fadd_rn(__fadd_rn(B1, A2), muc);
  float u  = __fsub_rn(prev, A2);
  maxA2 = fmaxf(maxA2, A2);
  minB1 = fminf(minB1, B1);
  bool  f1 = (B1 <= prev);
  bool  f2 = (u <= muc);
  float hi = f2 ? C  : B1;
  float lo = f2 ? B2 : prev;
  return f1 ? hi : lo;
}

template <bool WRITE>
__device__ __forceinline__ float run_chunk(const float4* __restrict__ xv,
                                           float4* __restrict__ ov, float p,
                                           float m_lo, float m_up, float mlc, float muc) {
#pragma unroll
  for (int i = 0; i < kL / 4; ++i) {
    float4 a = xv[i];
    float4 o;
    p = bstep(a.x, p, m_lo, m_up, mlc, muc); o.x = p;
    p = bstep(a.y, p, m_lo, m_up, mlc, muc); o.y = p;
    p = bstep(a.z, p, m_lo, m_up, mlc, muc); o.z = p;
    p = bstep(a.w, p, m_lo, m_up, mlc, muc); o.w = p;
    if (WRITE) ov[i] = o;
  }
  return p;
}

// Sweep 0: exits from guess (p0 for c==0, else 0.0) + identity-interval params.
__global__ __launch_bounds__(256) void sweep0(
    const float* __restrict__ x, const float* __restrict__ p0,
    const float* __restrict__ w, float* __restrict__ e0,
    float* __restrict__ a2m, float* __restrict__ b1m) {
  const int tid = blockIdx.x * 256 + threadIdx.x;
  const int r = tid >> 7, c = tid & (kNC - 1);
  const int idx = c * kB + r;
  const float m_lo = w[0], m_up = w[1];
  const float mlc = __fmul_rn(m_lo, w[2]), muc = __fmul_rn(m_up, w[3]);
  float p = (c == 0) ? p0[r] : 0.0f;
  float maxA2 = -__builtin_inff(), minB1 = __builtin_inff();
  const float4* xv = reinterpret_cast<const float4*>(x + (size_t)r * kT + c * kL);
#pragma unroll
  for (int i = 0; i < kL / 4; ++i) {
    float4 a = xv[i];
    p = bstep_track(a.x, p, m_lo, m_up, mlc, muc, maxA2, minB1);
    p = bstep_track(a.y, p, m_lo, m_up, mlc, muc, maxA2, minB1);
    p = bstep_track(a.z, p, m_lo, m_up, mlc, muc, maxA2, minB1);
    p = bstep_track(a.w, p, m_lo, m_up, mlc, muc, maxA2, minB1);
  }
  e0[idx] = p; a2m[idx] = maxA2; b1m[idx] = minB1;
}

// Sweep 1: exits chained from e0.
__global__ __launch_bounds__(256) void sweep1(
    const float* __restrict__ x, const float* __restrict__ p0,
    const float* __restrict__ w, const float* __restrict__ e0,
    float* __restrict__ e1) {
  const int tid = blockIdx.x * 256 + threadIdx.x;
  const int r = tid >> 7, c = tid & (kNC - 1);
  const int idx = c * kB + r;
  const float m_lo = w[0], m_up = w[1];
  const float mlc = __fmul_rn(m_lo, w[2]), muc = __fmul_rn(m_up, w[3]);
  const float entry = (c == 0) ? p0[r] : e0[idx - kB];
  const float4* xv = reinterpret_cast<const float4*>(x + (size_t)r * kT + c * kL);
  e1[idx] = run_chunk<false>(xv, nullptr, entry, m_lo, m_up, mlc, muc);
}

// Sweep 2: chained from e1, speculatively writes outputs, records exits e2.
__global__ __launch_bounds__(256) void sweep2w(
    const float* __restrict__ x, const float* __restrict__ p0,
    const float* __restrict__ w, const float* __restrict__ e1,
    float* __restrict__ e2, float* __restrict__ out) {
  const int tid = blockIdx.x * 256 + threadIdx.x;
  const int r = tid >> 7, c = tid & (kNC - 1);
  const int idx = c * kB + r;
  const float m_lo = w[0], m_up = w[1];
  const float mlc = __fmul_rn(m_lo, w[2]), muc = __fmul_rn(m_up, w[3]);
  const float entry = (c == 0) ? p0[r] : e1[idx - kB];
  const float4* xv = reinterpret_cast<const float4*>(x + (size_t)r * kT + c * kL);
  float4* ov = reinterpret_cast<float4*>(out + (size_t)r * kT + c * kL);
  e2[idx] = run_chunk<true>(xv, ov, entry, m_lo, m_up, mlc, muc);
}

// pass_b: per-row serial stitch over chunks. Acceptance order:
//   1) identity(t): chunk is pure passthrough for entry t => exit t   [O(1)]
//   2) used == t  : sweep2w ran this chunk from exactly t => exit e2  [O(1)]
//   3) fallback   : inline 64-step recompute                          [rare]
__global__ __launch_bounds__(64) void pass_b(
    const float* __restrict__ x, const float* __restrict__ p0,
    const float* __restrict__ w, const float* __restrict__ e1,
    const float* __restrict__ e2, const float* __restrict__ a2m,
    const float* __restrict__ b1m, float* __restrict__ ent) {
  const int r = blockIdx.x * 64 + threadIdx.x;
  const float m_lo = w[0], m_up = w[1];
  const float mlc = __fmul_rn(m_lo, w[2]), muc = __fmul_rn(m_up, w[3]);
  const float p0r = p0[r];
  float t = p0r;
  // software-pipelined loads (independent of t)
  float used_n = p0r, ex_n = e2[r], a2_n = a2m[r], b1_n = b1m[r];
#pragma unroll 1
  for (int c = 0; c < kNC; ++c) {
    const int idx = c * kB + r;
    const float used = used_n, ex = ex_n, a2 = a2_n, b1 = b1_n;
    if (c + 1 < kNC) {
      used_n = e1[idx];            // = e1[(c+1)-1][r]
      ex_n   = e2[idx + kB];
      a2_n   = a2m[idx + kB];
      b1_n   = b1m[idx + kB];
    }
    ent[idx] = t;
    const bool idok = (t < b1) && (__fsub_rn(t, a2) > muc);
    if (idok) {
      // t unchanged: pure identity chunk
    } else if (used == t) {
      t = ex;
    } else {
      const float4* xv = reinterpret_cast<const float4*>(x + (size_t)r * kT + c * kL);
      t = run_chunk<false>(xv, nullptr, t, m_lo, m_up, mlc, muc);
    }
  }
}

// Epilogue: re-derives pass_b's classification (same inputs => identical):
//   identity  -> fill chunk with constant t (sweep2w wrote garbage there)
//   spec-ok   -> nothing (sweep2w's writes are the truth)
//   otherwise -> recompute chunk from true entry and rewrite
__global__ __launch_bounds__(256) void epilogue(
    const float* __restrict__ x, const float* __restrict__ p0,
    const float* __restrict__ w, const float* __restrict__ e1,
    const float* __restrict__ a2m, const float* __restrict__ b1m,
    const float* __restrict__ ent, float* __restrict__ out) {
  const int tid = blockIdx.x * 256 + threadIdx.x;
  const int r = tid >> 7, c = tid & (kNC - 1);
  const int idx = c * kB + r;
  const float m_lo = w[0], m_up = w[1];
  const float mlc = __fmul_rn(m_lo, w[2]), muc = __fmul_rn(m_up, w[3]);
  const float t = ent[idx];
  const bool idok = (t < b1m[idx]) && (__fsub_rn(t, a2m[idx]) > muc);
  float4* ov = reinterpret_cast<float4*>(out + (size_t)r * kT + c * kL);
  if (idok) {
    const float4 fv = make_float4(t, t, t, t);
#pragma unroll
    for (int i = 0; i < kL / 4; ++i) ov[i] = fv;
    return;
  }
  const float used = (c == 0) ? p0[r] : e1[idx - kB];
  if (used == t) return;
  const float4* xv = reinterpret_cast<const float4*>(x + (size_t)r * kT + c * kL);
  run_chunk<true>(xv, ov, t, m_lo, m_up, mlc, muc);
}

}  // namespace

extern "C" void kernel_launch(void* const* d_in, const int* in_sizes, int n_in,
                              void* d_out, int out_size, void* d_ws, size_t ws_size,
                              hipStream_t stream) {
  const float* x  = (const float*)d_in[0];   // (B, T, 1) fp32
  const float* p0 = (const float*)d_in[1];   // (B, 1, 1) fp32
  const float* w  = (const float*)d_in[2];   // (4,) fp32
  float* out = (float*)d_out;                // (B, T, 1) fp32
  (void)in_sizes; (void)n_in; (void)out_size; (void)ws_size;

  float* e0  = (float*)d_ws;     // 1 MB (reused as ent after sweep1)
  float* e1  = e0 + kRC;         // 1 MB
  float* e2  = e1 + kRC;         // 1 MB
  float* a2m = e2 + kRC;         // 1 MB
  float* b1m = a2m + kRC;        // 1 MB
  float* ent = e0;

  const int nb = kRC / 256;      // 1024 blocks
  sweep0 <<<nb, 256, 0, stream>>>(x, p0, w, e0, a2m, b1m);
  sweep1 <<<nb, 256, 0, stream>>>(x, p0, w, e0, e1);
  sweep2w<<<nb, 256, 0, stream>>>(x, p0, w, e1, e2, out);
  pass_b <<<kB / 64, 64, 0, stream>>>(x, p0, w, e1, e2, a2m, b1m, ent);
  epilogue<<<nb, 256, 0, stream>>>(x, p0, w, e1, a2m, b1m, ent, out);
}

// Round 5
// 180.992 us; speedup vs baseline: 2.9252x; 1.4453x over previous
//
#include <hip/hip_runtime.h>

// BacklashNet: per-row nonlinear scan (backlash/hysteresis), parallelized by
// speculative chunking with EXACT identity-interval acceptance.
//
// Bit-exact step (no FMA contraction, reference op order):
//   A1=fl(m_lo*x); B1=fl(A1+mlc) ["lo"]; A2=fl(m_up*x); B2=fl(A2+muc) ["up"]
//   C=fl(fl(B1+A2)+muc); f1=(B1<=p) [sign-exact s1<=0]; f2=(fl(p-A2)<=muc)
//   out = f1 ? (f2?C:B1) : (f2?B2:p)
// Chunk (64 steps) is pure identity for entry p  <=>  p < min_t B1_t  AND
// fl(p - max_t A2_t) > muc   (RN-sub monotone in A2 => EXACT).
//
// Pipeline (out written exactly ONCE, by pass_c):
//   s0    : all chunks from guess; exits e0 + (a2m=max A2, b1m=min B1)
//   s1    : all chunks from e0[c-1]; identity-shortcut skips x entirely
//   pass_b: serial stitch; accept identity(t) or bitwise e0[c-1]==t -> e1[c];
//           rare inline fallback; writes true entries `ent`
//   pass_c: outputs from true entries; identity -> constant fill (no x read);
//           all stores via 65-pad LDS transpose -> 1KB coalesced dwordx4
//           (fixes R4's 2.1x partial-sector write amplification)
//
// Aux arrays in T-layout idx = r*kNC + c (coalesced for the sweep mapping).
// Workspace: 5 MB (e0,e1,a2m,b1m,ent).

namespace {

constexpr int kB  = 2048;
constexpr int kT  = 8192;
constexpr int kL  = 64;        // chunk length
constexpr int kNC = kT / kL;   // 128 chunks/row
constexpr int kRC = kB * kNC;  // 262144 row-chunks

__device__ __forceinline__ float bstep(float xv, float prev, float m_lo, float m_up,
                                       float mlc, float muc) {
  float A1 = __fmul_rn(m_lo, xv);
  float B1 = __fadd_rn(A1, mlc);
  float A2 = __fmul_rn(m_up, xv);
  float B2 = __fadd_rn(A2, muc);
  float C  = __fadd_rn(__fadd_rn(B1, A2), muc);
  float u  = __fsub_rn(prev, A2);
  bool  f1 = (B1 <= prev);
  bool  f2 = (u <= muc);
  float hi = f2 ? C  : B1;
  float lo = f2 ? B2 : prev;
  return f1 ? hi : lo;
}

__device__ __forceinline__ float bstep_track(float xv, float prev, float m_lo, float m_up,
                                             float mlc, float muc,
                                             float& maxA2, float& minB1) {
  float A1 = __fmul_rn(m_lo, xv);
  float B1 = __fadd_rn(A1, mlc);
  float A2 = __fmul_rn(m_up, xv);
  float B2 = __fadd_rn(A2, muc);
  float C  = __fadd_rn(__fadd_rn(B1, A2), muc);
  float u  = __fsub_rn(prev, A2);
  maxA2 = fmaxf(maxA2, A2);
  minB1 = fminf(minB1, B1);
  bool  f1 = (B1 <= prev);
  bool  f2 = (u <= muc);
  float hi = f2 ? C  : B1;
  float lo = f2 ? B2 : prev;
  return f1 ? hi : lo;
}

// Run a 64-step chunk out of a register buffer (16 float4 loads issued first
// => 16 loads in flight per wave, MLP instead of latency-serialization).
__device__ __forceinline__ float run_chunk_reg(const float4* __restrict__ xv, float p,
                                               float m_lo, float m_up, float mlc, float muc) {
  float4 xb[16];
#pragma unroll
  for (int q = 0; q < 16; ++q) xb[q] = xv[q];
#pragma unroll
  for (int q = 0; q < 16; ++q) {
    p = bstep(xb[q].x, p, m_lo, m_up, mlc, muc);
    p = bstep(xb[q].y, p, m_lo, m_up, mlc, muc);
    p = bstep(xb[q].z, p, m_lo, m_up, mlc, muc);
    p = bstep(xb[q].w, p, m_lo, m_up, mlc, muc);
  }
  return p;
}

// s0: every chunk from guess (p0 for c==0, else 0.0); exits + identity params.
__global__ __launch_bounds__(256, 4) void sweep0(
    const float* __restrict__ x, const float* __restrict__ p0,
    const float* __restrict__ w, float* __restrict__ e0,
    float* __restrict__ a2m, float* __restrict__ b1m) {
  const int tid = blockIdx.x * 256 + threadIdx.x;
  const int r = tid >> 7, c = tid & (kNC - 1);
  const int idx = r * kNC + c;                     // T-layout, wave-coalesced
  const float m_lo = w[0], m_up = w[1];
  const float mlc = __fmul_rn(m_lo, w[2]), muc = __fmul_rn(m_up, w[3]);
  const float4* xv = reinterpret_cast<const float4*>(x + (size_t)r * kT + c * kL);
  float4 xb[16];
#pragma unroll
  for (int q = 0; q < 16; ++q) xb[q] = xv[q];
  float p = (c == 0) ? p0[r] : 0.0f;
  float ma = -__builtin_inff(), mb = __builtin_inff();
#pragma unroll
  for (int q = 0; q < 16; ++q) {
    p = bstep_track(xb[q].x, p, m_lo, m_up, mlc, muc, ma, mb);
    p = bstep_track(xb[q].y, p, m_lo, m_up, mlc, muc, ma, mb);
    p = bstep_track(xb[q].z, p, m_lo, m_up, mlc, muc, ma, mb);
    p = bstep_track(xb[q].w, p, m_lo, m_up, mlc, muc, ma, mb);
  }
  e0[idx] = p; a2m[idx] = ma; b1m[idx] = mb;
}

// s1: every chunk from e0[c-1]; identity-shortcut avoids the x read.
__global__ __launch_bounds__(256, 4) void sweep1(
    const float* __restrict__ x, const float* __restrict__ p0,
    const float* __restrict__ w, const float* __restrict__ e0,
    const float* __restrict__ a2m, const float* __restrict__ b1m,
    float* __restrict__ e1) {
  const int tid = blockIdx.x * 256 + threadIdx.x;
  const int r = tid >> 7, c = tid & (kNC - 1);
  const int idx = r * kNC + c;
  const float m_lo = w[0], m_up = w[1];
  const float mlc = __fmul_rn(m_lo, w[2]), muc = __fmul_rn(m_up, w[3]);
  const float entry = (c == 0) ? p0[r] : e0[idx - 1];
  const bool idok = (entry < b1m[idx]) && (__fsub_rn(entry, a2m[idx]) > muc);
  float p = entry;
  if (!idok) {
    const float4* xv = reinterpret_cast<const float4*>(x + (size_t)r * kT + c * kL);
    p = run_chunk_reg(xv, entry, m_lo, m_up, mlc, muc);
  }
  e1[idx] = p;
}

// pass_b: per-row serial stitch. Accept order:
//   1) identity(t) via (a2m,b1m)            -> exit t          [O(1), exact]
//   2) e0[c-1] == t (s1 ran from exactly t) -> exit e1[c]      [O(1)]
//   3) inline 64-step recompute                                [rare]
__global__ __launch_bounds__(64) void pass_b(
    const float* __restrict__ x, const float* __restrict__ p0,
    const float* __restrict__ w, const float* __restrict__ e0,
    const float* __restrict__ e1, const float* __restrict__ a2m,
    const float* __restrict__ b1m, float* __restrict__ ent) {
  const int r = blockIdx.x * 64 + threadIdx.x;
  const float m_lo = w[0], m_up = w[1];
  const float mlc = __fmul_rn(m_lo, w[2]), muc = __fmul_rn(m_up, w[3]);
  const float p0r = p0[r];
  const int base = r * kNC;
  float t = p0r;
  // software-pipelined loads (independent of t); per-lane contiguous streams
  float used_n = p0r, ex_n = e1[base], a2_n = a2m[base], b1_n = b1m[base];
#pragma unroll 1
  for (int c = 0; c < kNC; ++c) {
    const int idx = base + c;
    const float used = used_n, ex = ex_n, a2 = a2_n, b1 = b1_n;
    if (c + 1 < kNC) {
      used_n = e0[idx];          // = e0[(c+1)-1]
      ex_n   = e1[idx + 1];
      a2_n   = a2m[idx + 1];
      b1_n   = b1m[idx + 1];
    }
    ent[idx] = t;
    const bool idok = (t < b1) && (__fsub_rn(t, a2) > muc);
    if (idok) {
      // pure identity chunk: t unchanged
    } else if (used == t) {
      t = ex;
    } else {
      const float4* xv = reinterpret_cast<const float4*>(x + (size_t)r * kT + c * kL);
      t = run_chunk_reg(xv, t, m_lo, m_up, mlc, muc);
    }
  }
}

// pass_c: write ALL outputs once, from true entries, via LDS transpose.
// One wave per 64 consecutive chunks (16 KB window) of one row-half.
// LDS layout: column per lane, row stride 65 floats (65 % 32 == 1 =>
// every access phase is <=2-way bank aliasing == free on CDNA4).
__global__ __launch_bounds__(64) void pass_c(
    const float* __restrict__ x, const float* __restrict__ w,
    const float* __restrict__ ent, const float* __restrict__ a2m,
    const float* __restrict__ b1m, float* __restrict__ out) {
  __shared__ float ob[64 * 65];
  const int r = blockIdx.x >> 1, h = blockIdx.x & 1;
  const int lane = threadIdx.x;
  const int c = h * 64 + lane;
  const int idx = r * kNC + c;                    // coalesced aux reads
  const float m_lo = w[0], m_up = w[1];
  const float mlc = __fmul_rn(m_lo, w[2]), muc = __fmul_rn(m_up, w[3]);
  const float t = ent[idx];
  const bool idok = (t < b1m[idx]) && (__fsub_rn(t, a2m[idx]) > muc);
  float* col = ob + lane * 65;
  if (idok) {
    // identity chunk: constant fill, no x traffic at all
#pragma unroll
    for (int q = 0; q < 64; ++q) col[q] = t;
  } else {
    const float4* xv = reinterpret_cast<const float4*>(x + (size_t)r * kT + c * kL);
    float4 xb[16];
#pragma unroll
    for (int q = 0; q < 16; ++q) xb[q] = xv[q];
    float p = t;
#pragma unroll
    for (int q = 0; q < 16; ++q) {
      p = bstep(xb[q].x, p, m_lo, m_up, mlc, muc); col[4 * q + 0] = p;
      p = bstep(xb[q].y, p, m_lo, m_up, mlc, muc); col[4 * q + 1] = p;
      p = bstep(xb[q].z, p, m_lo, m_up, mlc, muc); col[4 * q + 2] = p;
      p = bstep(xb[q].w, p, m_lo, m_up, mlc, muc); col[4 * q + 3] = p;
    }
  }
  __syncthreads();
  // coalesced flush: 16 x (64 lanes x 16 B) = 16 KB contiguous
  float4* o4 = reinterpret_cast<float4*>(out + (size_t)r * kT + h * (64 * kL));
#pragma unroll
  for (int j = 0; j < 16; ++j) {
    const int g = j * 64 + lane;
    const int cc = g >> 4, q = g & 15;
    const float* s = ob + cc * 65 + 4 * q;
    o4[g] = make_float4(s[0], s[1], s[2], s[3]);
  }
}

}  // namespace

extern "C" void kernel_launch(void* const* d_in, const int* in_sizes, int n_in,
                              void* d_out, int out_size, void* d_ws, size_t ws_size,
                              hipStream_t stream) {
  const float* x  = (const float*)d_in[0];   // (B, T, 1) fp32
  const float* p0 = (const float*)d_in[1];   // (B, 1, 1) fp32
  const float* w  = (const float*)d_in[2];   // (4,) fp32
  float* out = (float*)d_out;                // (B, T, 1) fp32
  (void)in_sizes; (void)n_in; (void)out_size; (void)ws_size;

  float* e0  = (float*)d_ws;     // 1 MB
  float* e1  = e0 + kRC;         // 1 MB
  float* a2m = e1 + kRC;         // 1 MB
  float* b1m = a2m + kRC;        // 1 MB
  float* ent = b1m + kRC;        // 1 MB

  const int nb = kRC / 256;      // 1024 blocks
  sweep0<<<nb, 256, 0, stream>>>(x, p0, w, e0, a2m, b1m);
  sweep1<<<nb, 256, 0, stream>>>(x, p0, w, e0, a2m, b1m, e1);
  pass_b<<<kB / 64, 64, 0, stream>>>(x, p0, w, e0, e1, a2m, b1m, ent);
  pass_c<<<kRC / 64, 64, 0, stream>>>(x, w, ent, a2m, b1m, out);
}